// Round 1
// baseline (365.651 us; speedup 1.0000x reference)
//
#include <hip/hip_runtime.h>

using short8 = __attribute__((ext_vector_type(8))) short;
using f32x4  = __attribute__((ext_vector_type(4))) float;

__device__ __forceinline__ float bf2f(unsigned short u) {
  union { unsigned int i; float f; } c; c.i = ((unsigned int)u) << 16; return c.f;
}
__device__ __forceinline__ unsigned short f2bf(float x) {
  union { float f; unsigned int i; } c; c.f = x;
  unsigned int r = c.i + 0x7fffu + ((c.i >> 16) & 1u);
  return (unsigned short)(r >> 16);
}

// ---------------- cast kernels ----------------
__global__ void cast2_kernel(const float* __restrict__ a, const float* __restrict__ b,
                             unsigned short* __restrict__ oa, unsigned short* __restrict__ ob,
                             int n4) {
  int stride = gridDim.x * blockDim.x;
  for (int i = blockIdx.x * blockDim.x + threadIdx.x; i < 2 * n4; i += stride) {
    const float4* s; ushort4* d; int j;
    if (i < n4) { s = (const float4*)a; d = (ushort4*)oa; j = i; }
    else        { s = (const float4*)b; d = (ushort4*)ob; j = i - n4; }
    float4 v = s[j];
    ushort4 o; o.x = f2bf(v.x); o.y = f2bf(v.y); o.z = f2bf(v.z); o.w = f2bf(v.w);
    d[j] = o;
  }
}

__global__ void castw_kernel(const float* __restrict__ wq, const float* __restrict__ wk,
                             const float* __restrict__ wv, const float* __restrict__ wm,
                             const float* __restrict__ w1, const float* __restrict__ w2,
                             unsigned short* __restrict__ dst) {
  int i = blockIdx.x * blockDim.x + threadIdx.x;  // total 655360
  if (i >= 655360) return;
  const float* s; int off;
  if      (i < 65536)  { s = wq; off = i; }
  else if (i < 131072) { s = wk; off = i - 65536; }
  else if (i < 196608) { s = wv; off = i - 131072; }
  else if (i < 262144) { s = wm; off = i - 196608; }
  else if (i < 524288) { s = w1; off = i - 262144; }
  else                 { s = w2; off = i - 524288; }
  dst[i] = f2bf(s[off]);
}

// ---------------- GEMM: C[M,O] = A[M,K] @ B[O,K]^T, bf16 in, f32 accum ----------------
enum { EPI_F32 = 0, EPI_ELU1_MASK = 1, EPI_MASK_SCALE = 2, EPI_RELU_BF16 = 3 };

template<int EPI>
__global__ __launch_bounds__(256)
void gemm_nt(const unsigned short* __restrict__ A, const unsigned short* __restrict__ B,
             void* __restrict__ Cout, const float* __restrict__ aux,
             int M, int O, int K, float scale) {
  __shared__ unsigned short As[128 * 64];
  __shared__ unsigned short Bs[128 * 64];
  const int t  = threadIdx.x;
  const int w  = t >> 6, l = t & 63;
  const int wr = w >> 1, wc = w & 1;
  const int lr = l & 15, kg = l >> 4;
  const int brow = blockIdx.x * 128, bcol = blockIdx.y * 128;
  const int rsub = l >> 3;                       // 0..7 (row within 8-row chunk)
  const int swz  = 8 * ((l & 7) ^ rsub);         // pre-swizzled source col (elems)

  f32x4 acc[4][4];
  f32x4 zero = {0.f, 0.f, 0.f, 0.f};
  #pragma unroll
  for (int m = 0; m < 4; m++)
    #pragma unroll
    for (int n = 0; n < 4; n++) acc[m][n] = zero;

  for (int k0 = 0; k0 < K; k0 += 64) {
    #pragma unroll
    for (int i = 0; i < 4; i++) {
      int c = w * 4 + i;                         // chunk 0..15, 1KB each
      int row = c * 8 + rsub;
      const unsigned short* ga = A + (size_t)(brow + row) * K + k0 + swz;
      const unsigned short* gb = B + (size_t)(bcol + row) * K + k0 + swz;
      __builtin_amdgcn_global_load_lds((__attribute__((address_space(1))) unsigned int*)ga,
          (__attribute__((address_space(3))) unsigned int*)(As + c * 512), 16, 0, 0);
      __builtin_amdgcn_global_load_lds((__attribute__((address_space(1))) unsigned int*)gb,
          (__attribute__((address_space(3))) unsigned int*)(Bs + c * 512), 16, 0, 0);
    }
    __syncthreads();
    #pragma unroll
    for (int kk = 0; kk < 2; kk++) {
      short8 af[4], bfr[4];
      #pragma unroll
      for (int m = 0; m < 4; m++) {
        int r = wr * 64 + m * 16 + lr;
        int cb = kk * 64 + kg * 16;
        af[m] = *(const short8*)((const char*)As + r * 128 + (cb ^ ((r & 7) << 4)));
      }
      #pragma unroll
      for (int n = 0; n < 4; n++) {
        int r = wc * 64 + n * 16 + lr;
        int cb = kk * 64 + kg * 16;
        bfr[n] = *(const short8*)((const char*)Bs + r * 128 + (cb ^ ((r & 7) << 4)));
      }
      #pragma unroll
      for (int m = 0; m < 4; m++)
        #pragma unroll
        for (int n = 0; n < 4; n++)
          acc[m][n] = __builtin_amdgcn_mfma_f32_16x16x32_bf16(af[m], bfr[n], acc[m][n], 0, 0, 0);
    }
    __syncthreads();
  }

  #pragma unroll
  for (int m = 0; m < 4; m++) {
    #pragma unroll
    for (int n = 0; n < 4; n++) {
      int col = bcol + wc * 64 + n * 16 + lr;
      #pragma unroll
      for (int j = 0; j < 4; j++) {
        int row = brow + wr * 64 + m * 16 + kg * 4 + j;
        float v = acc[m][n][j];
        size_t idx = (size_t)row * O + col;
        if (EPI == EPI_F32) {
          ((float*)Cout)[idx] = v;
        } else if (EPI == EPI_ELU1_MASK) {
          float e = v > 0.f ? v + 1.f : __expf(v);   // elu(v)+1
          ((unsigned short*)Cout)[idx] = f2bf(e * aux[row]);
        } else if (EPI == EPI_MASK_SCALE) {
          ((unsigned short*)Cout)[idx] = f2bf(v * aux[row] * scale);
        } else {  // EPI_RELU_BF16
          ((unsigned short*)Cout)[idx] = f2bf(v > 0.f ? v : 0.f);
        }
      }
    }
  }
}

// ---------------- KV = sum_s K^T V  (per n,h: 32x32), Ksum = sum_s K ----------------
__global__ __launch_bounds__(1024)
void kv_reduce(const unsigned short* __restrict__ Kb, const unsigned short* __restrict__ Vb,
               float* __restrict__ KV, float* __restrict__ Ksum) {
  const int S = 8192, CH = 512;
  int nh = blockIdx.y;                  // 0..31
  int n = nh >> 3, h = nh & 7;
  int t = threadIdx.x;
  int d = t >> 5, dv = t & 31;
  __shared__ float Ks[16][32], Vs[16][32];
  float acc = 0.f, ks = 0.f;
  int s0 = blockIdx.x * CH;
  for (int s = s0; s < s0 + CH; s += 16) {
    int rr = (t >> 5) & 15, cc = t & 31;
    size_t base = ((size_t)n * S + s + rr) * 256 + h * 32 + cc;
    if (t < 512) Ks[rr][cc] = bf2f(Kb[base]);
    else         Vs[rr][cc] = bf2f(Vb[base]);
    __syncthreads();
    #pragma unroll
    for (int si = 0; si < 16; si++) {
      float kk = Ks[si][d];
      acc += kk * Vs[si][dv];
      ks  += kk;
    }
    __syncthreads();
  }
  atomicAdd(&KV[((size_t)nh * 32 + d) * 32 + dv], acc);
  if (dv == 0) atomicAdd(&Ksum[nh * 32 + d], ks);
}

// ---------------- msg_pre[l, h*32+dv] = (Q . KV) * S / (Q . Ksum + eps) ----------------
__global__ __launch_bounds__(256)
void msg_apply(const unsigned short* __restrict__ Qb, const float* __restrict__ KV,
               const float* __restrict__ Ksum, unsigned short* __restrict__ Mb) {
  int row0 = blockIdx.x * 64;
  int n = row0 >> 13;                    // L = 8192 rows per n
  int t = threadIdx.x;
  int h = t >> 5, dv = t & 31;
  __shared__ float KVs[8192];            // 8 heads x 32 x 32
  __shared__ float Kss[256];
  __shared__ float qs[8][256];
  for (int i = t; i < 8192; i += 256) KVs[i] = KV[(size_t)n * 8192 + i];
  Kss[t] = Ksum[n * 256 + t];
  __syncthreads();
  for (int r8 = 0; r8 < 64; r8 += 8) {
    #pragma unroll
    for (int i = 0; i < 8; i++)
      qs[i][t] = bf2f(Qb[(size_t)(row0 + r8 + i) * 256 + t]);
    __syncthreads();
    for (int i = 0; i < 8; i++) {
      const float* q = &qs[i][h * 32];
      float zden = 0.f;
      #pragma unroll
      for (int d_ = 0; d_ < 32; d_++) zden += q[d_] * Kss[h * 32 + d_];
      float z = 8192.f / (zden + 1e-6f);
      float o = 0.f;
      const float* kvh = &KVs[h * 1024];
      #pragma unroll
      for (int d_ = 0; d_ < 32; d_++) o += q[d_] * kvh[d_ * 32 + dv];
      Mb[(size_t)(row0 + r8 + i) * 256 + h * 32 + dv] = f2bf(o * z);
    }
    __syncthreads();
  }
}

// ---------------- LayerNorm kernels ----------------
__device__ __forceinline__ float block_sum(float v, float* red) {
  #pragma unroll
  for (int o = 32; o; o >>= 1) v += __shfl_down(v, o, 64);
  __syncthreads();
  if ((threadIdx.x & 63) == 0) red[threadIdx.x >> 6] = v;
  __syncthreads();
  return red[0] + red[1] + red[2] + red[3];
}

__global__ __launch_bounds__(256)
void ln1_concat(const float* __restrict__ msg, const float* __restrict__ x,
                const float* __restrict__ g, const float* __restrict__ b,
                unsigned short* __restrict__ xc) {
  __shared__ float red[4];
  int row = blockIdx.x, t = threadIdx.x;
  float v = msg[(size_t)row * 256 + t];
  float mu  = block_sum(v, red) * (1.f / 256.f);
  float dvv = v - mu;
  float var = block_sum(dvv * dvv, red) * (1.f / 256.f);
  float y = dvv * rsqrtf(var + 1e-5f) * g[t] + b[t];
  xc[(size_t)row * 512 + t]       = f2bf(x[(size_t)row * 256 + t]);
  xc[(size_t)row * 512 + 256 + t] = f2bf(y);
}

__global__ __launch_bounds__(256)
void ln2_res(const float* __restrict__ hbuf, const float* __restrict__ x,
             const float* __restrict__ g, const float* __restrict__ b,
             float* __restrict__ out) {
  __shared__ float red[4];
  int row = blockIdx.x, t = threadIdx.x;
  float v = hbuf[(size_t)row * 256 + t];
  float mu  = block_sum(v, red) * (1.f / 256.f);
  float dvv = v - mu;
  float var = block_sum(dvv * dvv, red) * (1.f / 256.f);
  float y = dvv * rsqrtf(var + 1e-5f) * g[t] + b[t];
  out[(size_t)row * 256 + t] = x[(size_t)row * 256 + t] + y;
}

// ---------------- launch ----------------
extern "C" void kernel_launch(void* const* d_in, const int* in_sizes, int n_in,
                              void* d_out, int out_size, void* d_ws, size_t ws_size,
                              hipStream_t stream) {
  const float* x   = (const float*)d_in[0];
  const float* src = (const float*)d_in[1];
  const float* xm  = (const float*)d_in[2];
  const float* sm  = (const float*)d_in[3];
  const float* Wq  = (const float*)d_in[4];
  const float* Wk  = (const float*)d_in[5];
  const float* Wv  = (const float*)d_in[6];
  const float* Wm  = (const float*)d_in[7];
  const float* W1  = (const float*)d_in[8];
  const float* W2  = (const float*)d_in[9];
  const float* g1  = (const float*)d_in[10];
  const float* b1  = (const float*)d_in[11];
  const float* g2  = (const float*)d_in[12];
  const float* b2  = (const float*)d_in[13];
  float* out = (float*)d_out;
  char*  ws  = (char*)d_ws;

  // workspace layout (bytes). R1/R2/R3 are 33.5MB regions, reused over time.
  unsigned short* xb   = (unsigned short*)(ws);                    // R1a
  unsigned short* sb   = (unsigned short*)(ws + 16777216);         // R1b
  unsigned short* Qb   = (unsigned short*)(ws + 33554432);         // R2a
  unsigned short* Mb   = (unsigned short*)(ws + 50331648);         // R2b
  unsigned short* Kb   = (unsigned short*)(ws + 67108864);         // R3a
  unsigned short* Vb   = (unsigned short*)(ws + 83886080);         // R3b
  float*          msgf = (float*)(ws + 67108864);                  // overlays Kb/Vb
  unsigned short* xc   = (unsigned short*)(ws + 33554432);         // overlays Qb/Mb
  unsigned short* h1b  = (unsigned short*)(ws + 67108864);         // overlays msgf
  float*          h2f  = (float*)(ws);                             // overlays xb/sb
  float*          KV   = (float*)(ws + 100663296);                 // 131072 B
  float*          Ksm  = (float*)(ws + 100663296 + 131072);        // 4096 B
  unsigned short* Wb   = (unsigned short*)(ws + 100663296 + 135168);
  unsigned short* Wqb = Wb;
  unsigned short* Wkb = Wb + 65536;
  unsigned short* Wvb = Wb + 131072;
  unsigned short* Wmb = Wb + 196608;
  unsigned short* W1b = Wb + 262144;
  unsigned short* W2b = Wb + 524288;

  hipMemsetAsync(ws + 100663296, 0, 135168, stream);  // zero KV + Ksum

  cast2_kernel<<<2048, 256, 0, stream>>>(x, src, xb, sb, 2097152);
  castw_kernel<<<2560, 256, 0, stream>>>(Wq, Wk, Wv, Wm, W1, W2, Wb);

  // projections
  gemm_nt<EPI_ELU1_MASK><<<dim3(256, 2), 256, 0, stream>>>(xb, Wqb, (void*)Qb, xm, 32768, 256, 256, 0.f);
  gemm_nt<EPI_ELU1_MASK><<<dim3(256, 2), 256, 0, stream>>>(sb, Wkb, (void*)Kb, sm, 32768, 256, 256, 0.f);
  gemm_nt<EPI_MASK_SCALE><<<dim3(256, 2), 256, 0, stream>>>(sb, Wvb, (void*)Vb, sm, 32768, 256, 256, 1.f / 8192.f);

  // linear attention core
  kv_reduce<<<dim3(16, 32), 1024, 0, stream>>>(Kb, Vb, KV, Ksm);
  msg_apply<<<512, 256, 0, stream>>>(Qb, KV, Ksm, Mb);

  // merge heads
  gemm_nt<EPI_F32><<<dim3(256, 2), 256, 0, stream>>>(Mb, Wmb, (void*)msgf, nullptr, 32768, 256, 256, 0.f);
  ln1_concat<<<32768, 256, 0, stream>>>(msgf, x, g1, b1, xc);

  // MLP
  gemm_nt<EPI_RELU_BF16><<<dim3(256, 4), 256, 0, stream>>>(xc, W1b, (void*)h1b, nullptr, 32768, 512, 512, 0.f);
  gemm_nt<EPI_F32><<<dim3(256, 2), 256, 0, stream>>>(h1b, W2b, (void*)h2f, nullptr, 32768, 256, 512, 0.f);
  ln2_res<<<32768, 256, 0, stream>>>(h2f, x, g2, b2, out);
}